// Round 9
// baseline (88.420 us; speedup 1.0000x reference)
//
#include <hip/hip_runtime.h>
#include <math.h>

#define NTH 256
#define KREP 16   // diagnostic replication factor (output bit-identical to KREP=1)

__device__ __forceinline__ float frcp(float x) { return __builtin_amdgcn_rcpf(x); }

// Clip directed segment A->B against rotated rect (center (ocx,ocy), axis (c,s),
// half-extents heu,hev); return cross(A',B') of clipped sub-segment (0 if empty).
__device__ __forceinline__ float clip_cross(
    float ax, float ay, float bx, float by,
    float ocx, float ocy, float c, float s,
    float heu, float hev)
{
    float dx = bx - ax, dy = by - ay;
    float rx = ax - ocx, ry = ay - ocy;
    float s0u = rx*c + ry*s,  sdu = dx*c + dy*s;
    float s0v = ry*c - rx*s,  sdv = dy*c - dx*s;
    float iu = frcp(sdu), iv = frcp(sdv);
    float ta = (-heu - s0u)*iu, tb = (heu - s0u)*iu;
    float tc = (-hev - s0v)*iv, td = (hev - s0v)*iv;
    float tlu = fminf(ta, tb), thu = fmaxf(ta, tb);
    float tlv = fminf(tc, td), thv = fmaxf(tc, td);
    float tin  = fmaxf(fmaxf(tlu, tlv), 0.0f);
    float tout = fminf(fminf(thu, thv), 1.0f);
    bool ok = tin < tout;
    float Ax = ax + tin*dx,  Ay = ay + tin*dy;
    float Bx = ax + tout*dx, By = ay + tout*dy;
    float cr = Ax*By - Ay*Bx;
    return ok ? cr : 0.0f;
}

__device__ __forceinline__ float iou_loss_one(const float b1[7], const float b2[7], float w)
{
    float zmax = fminf(b1[2]+0.5f*b1[5], b2[2]+0.5f*b2[5]);
    float zmin = fmaxf(b1[2]-0.5f*b1[5], b2[2]-0.5f*b2[5]);
    float dz = fmaxf(zmax - zmin, 0.0f);
    float v1 = b1[3]*b1[4]*b1[5];
    float v2 = b2[3]*b2[4]*b2[5];

    float ox = b2[0] - b1[0], oy = b2[1] - b1[1];
    float ca1 = __cosf(b1[6]), sa1 = __sinf(b1[6]);
    float ca2 = __cosf(b2[6]), sa2 = __sinf(b2[6]);
    float hw1 = 0.5f*b1[3], hl1 = 0.5f*b1[4];
    float hw2 = 0.5f*b2[3], hl2 = 0.5f*b2[4];

    const float dxs[4] = {0.5f,-0.5f,-0.5f,0.5f};
    const float dys[4] = {0.5f,0.5f,-0.5f,-0.5f};
    float px[4], py[4], qx[4], qy[4];
    #pragma unroll
    for (int k = 0; k < 4; ++k) {
        float xs = dxs[k]*b1[3], ys = dys[k]*b1[4];
        px[k] = xs*ca1 - ys*sa1;
        py[k] = xs*sa1 + ys*ca1;
        float xs2 = dxs[k]*b2[3], ys2 = dys[k]*b2[4];
        qx[k] = ox + xs2*ca2 - ys2*sa2;
        qy[k] = oy + xs2*sa2 + ys2*ca2;
    }

    float s2 = 0.0f;
    #pragma unroll
    for (int k = 0; k < 4; ++k) {
        int kn = (k+1)&3;
        s2 += clip_cross(px[k],py[k], px[kn],py[kn], ox,oy, ca2,sa2, hw2,hl2);
        s2 += clip_cross(qx[k],qy[k], qx[kn],qy[kn], 0.0f,0.0f, ca1,sa1, hw1,hl1);
    }
    float area = 0.5f*fabsf(s2);

    float inter_vol = area * dz;
    float iou = inter_vol * frcp(v1 + v2 - inter_vol + 1e-8f);
    return (1.0f - iou) * w;
}

__global__ __launch_bounds__(NTH) void iou_loss_kernel(
    const float* __restrict__ pred, const float* __restrict__ target,
    const float* __restrict__ weight, float* __restrict__ partial, int n)
{
    int i = blockIdx.x * blockDim.x + threadIdx.x;
    float loss = 0.0f;
    if (i < n) {
        float b1[7], b2[7];
        #pragma unroll
        for (int j = 0; j < 7; ++j) { b1[j] = pred[i*7+j]; b2[j] = target[i*7+j]; }
        float w = weight[i];

        // ---- DIAGNOSTIC: recompute KREP times; asm barriers defeat CSE/DCE.
        // Output is bit-identical to a single evaluation (loss = last iter).
        float lk = 0.0f;
        #pragma unroll 1
        for (int k = 0; k < KREP; ++k) {
            float c1[7], c2[7];
            #pragma unroll
            for (int j2 = 0; j2 < 7; ++j2) {
                c1[j2] = b1[j2]; c2[j2] = b2[j2];
                asm volatile("" : "+v"(c1[j2]), "+v"(c2[j2]));
            }
            float ww = w;
            asm volatile("" : "+v"(ww));
            lk = iou_loss_one(c1, c2, ww);
            asm volatile("" :: "v"(lk));   // keep every iteration live
        }
        loss = lk;
    }

    // block reduction -> per-block partial (no atomics, no fences)
    #pragma unroll
    for (int off = 32; off > 0; off >>= 1) loss += __shfl_down(loss, off, 64);
    __shared__ float wsum[NTH/64];
    int lane = threadIdx.x & 63, wid = threadIdx.x >> 6;
    if (lane == 0) wsum[wid] = loss;
    __syncthreads();
    if (threadIdx.x == 0) {
        float s = 0.0f;
        #pragma unroll
        for (int w = 0; w < NTH/64; ++w) s += wsum[w];
        partial[blockIdx.x] = s;
    }
}

__global__ __launch_bounds__(NTH) void reduce_kernel(
    const float* __restrict__ partial, int nb, float* __restrict__ out, double inv_n)
{
    double s = 0.0;
    for (int j = threadIdx.x; j < nb; j += NTH) s += (double)partial[j];
    #pragma unroll
    for (int off = 32; off > 0; off >>= 1) s += __shfl_down(s, off, 64);
    __shared__ double wsum[NTH/64];
    int lane = threadIdx.x & 63, wid = threadIdx.x >> 6;
    if (lane == 0) wsum[wid] = s;
    __syncthreads();
    if (threadIdx.x == 0) {
        double tot = 0.0;
        #pragma unroll
        for (int w = 0; w < NTH/64; ++w) tot += wsum[w];
        out[0] = (float)(tot * inv_n);
    }
}

extern "C" void kernel_launch(void* const* d_in, const int* in_sizes, int n_in,
                              void* d_out, int out_size, void* d_ws, size_t ws_size,
                              hipStream_t stream) {
    const float* pred   = (const float*)d_in[0];
    const float* target = (const float*)d_in[1];
    const float* weight = (const float*)d_in[2];
    int n = in_sizes[2];
    float* partial = (float*)d_ws;
    int nblocks = (n + NTH - 1) / NTH;
    hipLaunchKernelGGL(iou_loss_kernel, dim3(nblocks), dim3(NTH), 0, stream,
                       pred, target, weight, partial, n);
    hipLaunchKernelGGL(reduce_kernel, dim3(1), dim3(NTH), 0, stream,
                       partial, nblocks, (float*)d_out, 1.0 / (double)n);
}

// Round 11
// 13.417 us; speedup vs baseline: 6.5902x; 6.5902x over previous
//
#include <hip/hip_runtime.h>
#include <math.h>

#define NTH 256

__device__ __forceinline__ float frcp(float x) { return __builtin_amdgcn_rcpf(x); }

__device__ __forceinline__ float iou_loss_one(const float b1[7], const float b2[7], float w)
{
    // z overlap + volumes
    float zmax = fminf(b1[2]+0.5f*b1[5], b2[2]+0.5f*b2[5]);
    float zmin = fmaxf(b1[2]-0.5f*b1[5], b2[2]-0.5f*b2[5]);
    float dz = fmaxf(zmax - zmin, 0.0f);
    float v1 = b1[3]*b1[4]*b1[5];
    float v2 = b2[3]*b2[4]*b2[5];

    float hw1 = 0.5f*b1[3], hl1 = 0.5f*b1[4];
    float hw2 = 0.5f*b2[3], hl2 = 0.5f*b2[4];

    // Frame1: rotate by -a1 about box1 center. Box1 -> axis-aligned at origin.
    float da = b2[6] - b1[6];
    float ct = __cosf(da), st = __sinf(da);
    float ca1 = __cosf(b1[6]), sa1 = __sinf(b1[6]);
    float ox = b2[0] - b1[0], oy = b2[1] - b1[1];
    float Ox =  ox*ca1 + oy*sa1;     // box2 center in frame1
    float Oy =  oy*ca1 - ox*sa1;

    // box2 half-edge vectors in frame1
    float ux = hw2*ct, uy = hw2*st;
    float vx = -hl2*st, vy = hl2*ct;

    // box2 corners (CCW): q0=O+u+v, q1=O-u+v, q2=O-u-v, q3=O+u-v
    float wx_ = ux+vx, wy_ = uy+vy, zx_ = ux-vx, zy_ = uy-vy;
    float q0x = Ox+wx_, q0y = Oy+wy_;
    float q1x = Ox-zx_, q1y = Oy-zy_;
    float q2x = Ox-wx_, q2y = Oy-wy_;
    float q3x = Ox+zx_, q3y = Oy+zy_;

    // shared reciprocals for box2 edge dirs (+-2u, +-2v)
    float i2ux = frcp(ux+ux), i2uy = frcp(uy+uy);
    float i2vx = frcp(vx+vx), i2vy = frcp(vy+vy);

    float s2 = 0.0f;

    // ---- clip box2 edges against |x|<=hw1, |y|<=hl1 (axis-aligned LB) ----
    #define CLIP_Q(AX,AY,DX,DY,IUX,IUY)  {                                  \
        float ta = (-hw1 - (AX))*(IUX), tb = (hw1 - (AX))*(IUX);            \
        float tc = (-hl1 - (AY))*(IUY), td = (hl1 - (AY))*(IUY);            \
        float tlu = fminf(ta,tb), thu = fmaxf(ta,tb);                       \
        float tlv = fminf(tc,td), thv = fmaxf(tc,td);                       \
        float tin  = fmaxf(fmaxf(tlu,tlv), 0.0f);                           \
        float tout = fminf(fminf(thu,thv), 1.0f);                           \
        bool ok = tin < tout;                                               \
        float Apx = (AX) + tin*(DX),  Apy = (AY) + tin*(DY);                \
        float Bpx = (AX) + tout*(DX), Bpy = (AY) + tout*(DY);               \
        float cr = Apx*Bpy - Apy*Bpx;                                       \
        s2 += ok ? cr : 0.0f; }

    CLIP_Q(q0x,q0y, -(ux+ux), -(uy+uy), -i2ux, -i2uy)   // q0->q1, d=-2u
    CLIP_Q(q1x,q1y, -(vx+vx), -(vy+vy), -i2vx, -i2vy)   // q1->q2, d=-2v
    CLIP_Q(q2x,q2y,  (ux+ux),  (uy+uy),  i2ux,  i2uy)   // q2->q3, d=+2u
    CLIP_Q(q3x,q3y,  (vx+vx),  (vy+vy),  i2vx,  i2vy)   // q3->q0, d=+2v
    #undef CLIP_Q

    // ---- clip box1 edges against box2 slabs; cross-sum collapses to
    //      2*hw1*hl1 * sum(tout-tin)  per edge (axis-aligned segments) ----
    #define PROJ(PX,PY,PU,PV) { float rx=(PX)-Ox, ry=(PY)-Oy;               \
        PU = rx*ct + ry*st;  PV = ry*ct - rx*st; }
    float p0u,p0v,p1u,p1v,p2u,p2v,p3u,p3v;
    PROJ( hw1,  hl1, p0u,p0v)
    PROJ(-hw1,  hl1, p1u,p1v)
    PROJ(-hw1, -hl1, p2u,p2v)
    PROJ( hw1, -hl1, p3u,p3v)
    #undef PROJ

    float Au = (hw1+hw1)*ct, Av = (hw1+hw1)*st;
    float Cu = (hl1+hl1)*st, Cv = (hl1+hl1)*ct;
    float iAu = frcp(Au), iAv = frcp(Av), iCu = frcp(Cu), iCv = frcp(Cv);

    float sdt = 0.0f;
    #define CLIP_P(PU,PV,IDU,IDV) {                                         \
        float ta = (-hw2 - (PU))*(IDU), tb = (hw2 - (PU))*(IDU);            \
        float tc = (-hl2 - (PV))*(IDV), td = (hl2 - (PV))*(IDV);            \
        float tlu = fminf(ta,tb), thu = fmaxf(ta,tb);                       \
        float tlv = fminf(tc,td), thv = fmaxf(tc,td);                       \
        float tin  = fmaxf(fmaxf(tlu,tlv), 0.0f);                           \
        float tout = fminf(fminf(thu,thv), 1.0f);                           \
        float dt = tout - tin;                                              \
        sdt += (dt > 0.0f) ? dt : 0.0f; }

    CLIP_P(p0u,p0v, -iAu,  iAv)   // e0: p0->p1, d=(-2hw1,0)
    CLIP_P(p1u,p1v, -iCu, -iCv)   // e1: p1->p2, d=(0,-2hl1)
    CLIP_P(p2u,p2v,  iAu, -iAv)   // e2: p2->p3, d=(2hw1,0)
    CLIP_P(p3u,p3v,  iCu,  iCv)   // e3: p3->p0, d=(0,2hl1)
    #undef CLIP_P

    // each box1 edge contributes 2*hw1*hl1*dt  (NOT 4*hw1*hl1 — R10 bug)
    s2 += (hw1+hw1)*hl1*sdt;

    float area = 0.5f*fabsf(s2);
    float inter_vol = area * dz;
    float iou = inter_vol * frcp(v1 + v2 - inter_vol + 1e-8f);
    return (1.0f - iou) * w;
}

__global__ __launch_bounds__(NTH) void iou_loss_kernel(
    const float* __restrict__ pred, const float* __restrict__ target,
    const float* __restrict__ weight, float* __restrict__ partial, int n)
{
    int i = blockIdx.x * blockDim.x + threadIdx.x;
    float loss = 0.0f;
    if (i < n) {
        float b1[7], b2[7];
        #pragma unroll
        for (int j = 0; j < 7; ++j) { b1[j] = pred[i*7+j]; b2[j] = target[i*7+j]; }
        loss = iou_loss_one(b1, b2, weight[i]);
    }

    // block reduction -> per-block partial (no atomics, no fences)
    #pragma unroll
    for (int off = 32; off > 0; off >>= 1) loss += __shfl_down(loss, off, 64);
    __shared__ float wsum[NTH/64];
    int lane = threadIdx.x & 63, wid = threadIdx.x >> 6;
    if (lane == 0) wsum[wid] = loss;
    __syncthreads();
    if (threadIdx.x == 0) {
        float s = 0.0f;
        #pragma unroll
        for (int w = 0; w < NTH/64; ++w) s += wsum[w];
        partial[blockIdx.x] = s;
    }
}

__global__ __launch_bounds__(NTH) void reduce_kernel(
    const float* __restrict__ partial, int nb, float* __restrict__ out, double inv_n)
{
    double s = 0.0;
    for (int j = threadIdx.x; j < nb; j += NTH) s += (double)partial[j];
    #pragma unroll
    for (int off = 32; off > 0; off >>= 1) s += __shfl_down(s, off, 64);
    __shared__ double wsum[NTH/64];
    int lane = threadIdx.x & 63, wid = threadIdx.x >> 6;
    if (lane == 0) wsum[wid] = s;
    __syncthreads();
    if (threadIdx.x == 0) {
        double tot = 0.0;
        #pragma unroll
        for (int w = 0; w < NTH/64; ++w) tot += wsum[w];
        out[0] = (float)(tot * inv_n);
    }
}

extern "C" void kernel_launch(void* const* d_in, const int* in_sizes, int n_in,
                              void* d_out, int out_size, void* d_ws, size_t ws_size,
                              hipStream_t stream) {
    const float* pred   = (const float*)d_in[0];
    const float* target = (const float*)d_in[1];
    const float* weight = (const float*)d_in[2];
    int n = in_sizes[2];
    float* partial = (float*)d_ws;
    int nblocks = (n + NTH - 1) / NTH;
    hipLaunchKernelGGL(iou_loss_kernel, dim3(nblocks), dim3(NTH), 0, stream,
                       pred, target, weight, partial, n);
    hipLaunchKernelGGL(reduce_kernel, dim3(1), dim3(NTH), 0, stream,
                       partial, nblocks, (float*)d_out, 1.0 / (double)n);
}

// Round 12
// 13.097 us; speedup vs baseline: 6.7510x; 1.0244x over previous
//
#include <hip/hip_runtime.h>
#include <math.h>

#define NTH 256
#define G   4
#define RPB (NTH*G)   // rows per block

__device__ __forceinline__ float frcp(float x) { return __builtin_amdgcn_rcpf(x); }

__device__ __forceinline__ float iou_loss_one(const float b1[7], const float b2[7], float w)
{
    // z overlap + volumes
    float zmax = fminf(b1[2]+0.5f*b1[5], b2[2]+0.5f*b2[5]);
    float zmin = fmaxf(b1[2]-0.5f*b1[5], b2[2]-0.5f*b2[5]);
    float dz = fmaxf(zmax - zmin, 0.0f);
    float v1 = b1[3]*b1[4]*b1[5];
    float v2 = b2[3]*b2[4]*b2[5];

    float hw1 = 0.5f*b1[3], hl1 = 0.5f*b1[4];
    float hw2 = 0.5f*b2[3], hl2 = 0.5f*b2[4];

    // Frame1: rotate by -a1 about box1 center. Box1 -> axis-aligned at origin.
    float ca1 = __cosf(b1[6]), sa1 = __sinf(b1[6]);
    float ca2 = __cosf(b2[6]), sa2 = __sinf(b2[6]);
    // angle-difference identities: 2 fewer transcendentals
    float ct = ca2*ca1 + sa2*sa1;    // cos(a2-a1)
    float st = sa2*ca1 - ca2*sa1;    // sin(a2-a1)
    float ox = b2[0] - b1[0], oy = b2[1] - b1[1];
    float Ox =  ox*ca1 + oy*sa1;     // box2 center in frame1
    float Oy =  oy*ca1 - ox*sa1;

    // box2 half-edge vectors in frame1
    float ux = hw2*ct, uy = hw2*st;
    float vx = -hl2*st, vy = hl2*ct;

    // box2 corners (CCW): q0=O+u+v, q1=O-u+v, q2=O-u-v, q3=O+u-v
    float wx_ = ux+vx, wy_ = uy+vy, zx_ = ux-vx, zy_ = uy-vy;
    float q0x = Ox+wx_, q0y = Oy+wy_;
    float q1x = Ox-zx_, q1y = Oy-zy_;
    float q2x = Ox-wx_, q2y = Oy-wy_;
    float q3x = Ox+zx_, q3y = Oy+zy_;

    // shared reciprocals for box2 edge dirs (+-2u, +-2v)
    float i2ux = frcp(ux+ux), i2uy = frcp(uy+uy);
    float i2vx = frcp(vx+vx), i2vy = frcp(vy+vy);

    float s2 = 0.0f;

    // ---- clip box2 edges against |x|<=hw1, |y|<=hl1 (axis-aligned LB) ----
    #define CLIP_Q(AX,AY,DX,DY,IUX,IUY)  {                                  \
        float ta = (-hw1 - (AX))*(IUX), tb = (hw1 - (AX))*(IUX);            \
        float tc = (-hl1 - (AY))*(IUY), td = (hl1 - (AY))*(IUY);            \
        float tlu = fminf(ta,tb), thu = fmaxf(ta,tb);                       \
        float tlv = fminf(tc,td), thv = fmaxf(tc,td);                       \
        float tin  = fmaxf(fmaxf(tlu,tlv), 0.0f);                           \
        float tout = fminf(fminf(thu,thv), 1.0f);                           \
        bool ok = tin < tout;                                               \
        float Apx = (AX) + tin*(DX),  Apy = (AY) + tin*(DY);                \
        float Bpx = (AX) + tout*(DX), Bpy = (AY) + tout*(DY);               \
        float cr = Apx*Bpy - Apy*Bpx;                                       \
        s2 += ok ? cr : 0.0f; }

    CLIP_Q(q0x,q0y, -(ux+ux), -(uy+uy), -i2ux, -i2uy)   // q0->q1, d=-2u
    CLIP_Q(q1x,q1y, -(vx+vx), -(vy+vy), -i2vx, -i2vy)   // q1->q2, d=-2v
    CLIP_Q(q2x,q2y,  (ux+ux),  (uy+uy),  i2ux,  i2uy)   // q2->q3, d=+2u
    CLIP_Q(q3x,q3y,  (vx+vx),  (vy+vy),  i2vx,  i2vy)   // q3->q0, d=+2v
    #undef CLIP_Q

    // ---- clip box1 edges against box2 slabs; each contributes
    //      2*hw1*hl1*(tout-tin) to the cross-sum ----
    float Au = (hw1+hw1)*ct, Av = (hw1+hw1)*st;
    float Cu = (hl1+hl1)*st, Cv = (hl1+hl1)*ct;
    float iAu = frcp(Au), iAv = frcp(Av), iCu = frcp(Cu), iCv = frcp(Cv);

    // corner p0=(hw1,hl1) projected into box2 frame; chain the rest
    float rx = hw1 - Ox, ry = hl1 - Oy;
    float p0u = rx*ct + ry*st,  p0v = ry*ct - rx*st;
    float p1u = p0u - Au, p1v = p0v + Av;   // p1 = p0 + (-2hw1, 0)
    float p2u = p1u - Cu, p2v = p1v - Cv;   // p2 = p1 + (0, -2hl1)
    float p3u = p0u - Cu, p3v = p0v - Cv;   // p3 = p0 + (0, -2hl1)

    float sdt = 0.0f;
    #define CLIP_P(PU,PV,IDU,IDV) {                                         \
        float ta = (-hw2 - (PU))*(IDU), tb = (hw2 - (PU))*(IDU);            \
        float tc = (-hl2 - (PV))*(IDV), td = (hl2 - (PV))*(IDV);            \
        float tlu = fminf(ta,tb), thu = fmaxf(ta,tb);                       \
        float tlv = fminf(tc,td), thv = fmaxf(tc,td);                       \
        float tin  = fmaxf(fmaxf(tlu,tlv), 0.0f);                           \
        float tout = fminf(fminf(thu,thv), 1.0f);                           \
        float dt = tout - tin;                                              \
        sdt += (dt > 0.0f) ? dt : 0.0f; }

    CLIP_P(p0u,p0v, -iAu,  iAv)   // e0: p0->p1, d=(-2hw1,0)
    CLIP_P(p1u,p1v, -iCu, -iCv)   // e1: p1->p2, d=(0,-2hl1)
    CLIP_P(p2u,p2v,  iAu, -iAv)   // e2: p2->p3, d=(2hw1,0)
    CLIP_P(p3u,p3v,  iCu,  iCv)   // e3: p3->p0, d=(0,2hl1)
    #undef CLIP_P

    s2 += (hw1+hw1)*hl1*sdt;      // 2*hw1*hl1 per unit dt

    float area = 0.5f*fabsf(s2);
    float inter_vol = area * dz;
    float iou = inter_vol * frcp(v1 + v2 - inter_vol + 1e-8f);
    return (1.0f - iou) * w;
}

__global__ __launch_bounds__(NTH) void iou_loss_kernel(
    const float* __restrict__ pred, const float* __restrict__ target,
    const float* __restrict__ weight, float* __restrict__ partial, int n)
{
    const int tid = threadIdx.x;
    const int row0 = blockIdx.x * RPB;
    float loss = 0.0f;

    float b1[G][7], b2[G][7], wv[G];
    #define LOADG(g, i) {                                                   \
        _Pragma("unroll")                                                   \
        for (int j = 0; j < 7; ++j) {                                       \
            b1[g][j] = pred[(i)*7+j]; b2[g][j] = target[(i)*7+j]; }         \
        wv[g] = weight[i]; }

    if (row0 + RPB <= n) {
        // software pipeline: issue loads for g+1 above compute of g
        LOADG(0, row0 + tid)
        #pragma unroll
        for (int g = 0; g < G; ++g) {
            if (g + 1 < G) LOADG(g + 1, row0 + (g + 1) * NTH + tid)
            loss += iou_loss_one(b1[g], b2[g], wv[g]);
        }
    } else {
        #pragma unroll
        for (int g = 0; g < G; ++g) {
            int i = row0 + g * NTH + tid;
            if (i < n) {
                LOADG(g, i)
                loss += iou_loss_one(b1[g], b2[g], wv[g]);
            }
        }
    }
    #undef LOADG

    // block reduction -> per-block partial (no atomics, no fences)
    #pragma unroll
    for (int off = 32; off > 0; off >>= 1) loss += __shfl_down(loss, off, 64);
    __shared__ float wsum[NTH/64];
    int lane = tid & 63, wid = tid >> 6;
    if (lane == 0) wsum[wid] = loss;
    __syncthreads();
    if (tid == 0) {
        float s = 0.0f;
        #pragma unroll
        for (int w = 0; w < NTH/64; ++w) s += wsum[w];
        partial[blockIdx.x] = s;
    }
}

__global__ __launch_bounds__(NTH) void reduce_kernel(
    const float* __restrict__ partial, int nb, float* __restrict__ out, double inv_n)
{
    double s = 0.0;
    for (int j = threadIdx.x; j < nb; j += NTH) s += (double)partial[j];
    #pragma unroll
    for (int off = 32; off > 0; off >>= 1) s += __shfl_down(s, off, 64);
    __shared__ double wsum[NTH/64];
    int lane = threadIdx.x & 63, wid = threadIdx.x >> 6;
    if (lane == 0) wsum[wid] = s;
    __syncthreads();
    if (threadIdx.x == 0) {
        double tot = 0.0;
        #pragma unroll
        for (int w = 0; w < NTH/64; ++w) tot += wsum[w];
        out[0] = (float)(tot * inv_n);
    }
}

extern "C" void kernel_launch(void* const* d_in, const int* in_sizes, int n_in,
                              void* d_out, int out_size, void* d_ws, size_t ws_size,
                              hipStream_t stream) {
    const float* pred   = (const float*)d_in[0];
    const float* target = (const float*)d_in[1];
    const float* weight = (const float*)d_in[2];
    int n = in_sizes[2];
    float* partial = (float*)d_ws;
    int nblocks = (n + RPB - 1) / RPB;
    hipLaunchKernelGGL(iou_loss_kernel, dim3(nblocks), dim3(NTH), 0, stream,
                       pred, target, weight, partial, n);
    hipLaunchKernelGGL(reduce_kernel, dim3(1), dim3(NTH), 0, stream,
                       partial, nblocks, (float*)d_out, 1.0 / (double)n);
}